// Round 4
// baseline (59.309 us; speedup 1.0000x reference)
//
#include <hip/hip_runtime.h>
#include <hip/hip_bf16.h>
#include <math.h>

// SimCLR NT-Xent: B=4096, D=256, n=8192, T=0.5.
// z = rownorm(concat(a,b)) stored bf16, row-swizzled:
//   stored_byte_in_row = logical_byte ^ ((row&7)<<4)
// E_ij = exp(2*dot_ij - 2) = exp2(dot*K1 - K1).  E is SYMMETRIC.
// Triangular tiling: 128x128 tiles, blocks (t,u) with t<=u compute the tile
// once and emit BOTH row-sums (rows of t, slot u) and col-sums (rows of u,
// slot t). s_part[i*64+slot] each written exactly once (no atomics).
// loss = mean(2 + ln(S_i - E_ii) - 2*posdot_i).

#define NROWS 8192
#define BHALF 4096
#define DDIM  256
#define ROWB  512                 // bytes per bf16 row
#define NT    64                  // number of 128-row tiles
#define JT    64                  // cols per pipeline step
#define NSTEPS 2                  // 128 cols per tile
#define TILEB (JT * ROWB)         // 32 KiB per LDS buffer

#define K1F 2.8853900817779268f   // 2*log2(e)
#define LN2F 0.6931471805599453f

typedef __attribute__((ext_vector_type(8))) __bf16 bf16x8;
typedef __attribute__((ext_vector_type(4))) float f32x4;

#if __has_builtin(__builtin_amdgcn_exp2f)
#define FEXP2(x) __builtin_amdgcn_exp2f(x)
#else
#define FEXP2(x) __exp2f(x)
#endif
#if __has_builtin(__builtin_amdgcn_logf)
#define FLOG2(x) __builtin_amdgcn_logf(x)
#else
#define FLOG2(x) __log2f(x)
#endif

__device__ __forceinline__ float bfu(unsigned short u) {
  union { unsigned v; float f; } x; x.v = ((unsigned)u) << 16; return x.f;
}

// ---------------- Kernel 1: normalize rows -> swizzled bf16 z + selfdot ----
__global__ __launch_bounds__(256) void norm_kernel(
    const float* __restrict__ a, const float* __restrict__ b,
    char* __restrict__ zb, float* __restrict__ selfdot) {
  int row = blockIdx.x * 4 + (threadIdx.x >> 6);
  int lane = threadIdx.x & 63;
  const float* src = (row < BHALF) ? (a + (size_t)row * DDIM)
                                   : (b + (size_t)(row - BHALF) * DDIM);
  float4 v = ((const float4*)src)[lane];
  float ss = v.x * v.x + v.y * v.y + v.z * v.z + v.w * v.w;
  #pragma unroll
  for (int m = 1; m < 64; m <<= 1) ss += __shfl_xor(ss, m, 64);
  float inv = rsqrtf(ss);
  inv = inv * (1.5f - 0.5f * ss * inv * inv);

  union { __hip_bfloat16 h; unsigned short u; } c0, c1, c2, c3;
  c0.h = __float2bfloat16(v.x * inv);
  c1.h = __float2bfloat16(v.y * inv);
  c2.h = __float2bfloat16(v.z * inv);
  c3.h = __float2bfloat16(v.w * inv);
  float q0 = bfu(c0.u), q1 = bfu(c1.u), q2 = bfu(c2.u), q3 = bfu(c3.u);
  float sq = q0 * q0 + q1 * q1 + q2 * q2 + q3 * q3;
  #pragma unroll
  for (int m = 1; m < 64; m <<= 1) sq += __shfl_xor(sq, m, 64);

  ushort4 o = make_ushort4(c0.u, c1.u, c2.u, c3.u);
  int off = row * ROWB + ((lane * 8) ^ ((row & 7) << 4));
  *(ushort4*)(zb + off) = o;
  if (lane == 0) selfdot[row] = sq;
}

// ---------------- Kernel 2: triangular z z^T + exp-sum ---------------------
// 2080 blocks = tiles (t,u), t<=u, of 128x128. 256 threads = 4 waves,
// each wave owns 32 rows (A in 64 VGPRs over K=256). B: 2 steps of 64 cols,
// double-buffered LDS via global_load_lds.
__global__ __launch_bounds__(256, 2) void sim_kernel(
    const char* __restrict__ zb, float* __restrict__ s_part) {
  __shared__ __align__(16) char lds[2 * TILEB];  // 64 KiB
  __shared__ float cred[4][128];                 // col-sum cross-wave buffer

  // block -> (t,u), t<=u
  int t = 0, rem = blockIdx.x;
  while (rem >= NT - t) { rem -= NT - t; ++t; }
  int u = t + rem;

  int wave = threadIdx.x >> 6;
  int lane = threadIdx.x & 63;
  int lrow = lane & 15;
  int kgrp = lane >> 4;
  int sw = (lrow & 7) << 4;
  int r0 = t * 128 + wave * 32;
  int jbase = u * 128;

  int koff[8];
  #pragma unroll
  for (int kk = 0; kk < 8; ++kk) koff[kk] = (kk * 64 + kgrp * 16) ^ sw;

  // --- preload A fragments (32 rows x K=256) ---
  bf16x8 af[2][8];
  #pragma unroll
  for (int rf = 0; rf < 2; ++rf) {
    const char* rp = zb + (size_t)(r0 + rf * 16 + lrow) * ROWB;
    #pragma unroll
    for (int kk = 0; kk < 8; ++kk)
      af[rf][kk] = *(const bf16x8*)(rp + koff[kk]);
  }

  float sacc[2][4] = {};  // row-sum acc: [rf][r]
  float cacc[8] = {};     // col-sum acc: [s*4+ct], col = idx*16+lrow

  #define STAGE(buf, j0) do {                                                 \
    const char* g_ = zb + (size_t)(j0) * ROWB + wave * 8192 + lane * 16;      \
    char* l_ = lds + (buf) * TILEB + wave * 8192;                             \
    _Pragma("unroll")                                                         \
    for (int c8 = 0; c8 < 8; ++c8)                                            \
      __builtin_amdgcn_global_load_lds(                                       \
          (const __attribute__((address_space(1))) void*)(g_ + c8 * 1024),    \
          (__attribute__((address_space(3))) void*)(l_ + c8 * 1024),          \
          16, 0, 0);                                                          \
  } while (0)

  STAGE(0, jbase);
  __syncthreads();

  #pragma unroll
  for (int s = 0; s < NSTEPS; ++s) {
    if (s + 1 < NSTEPS) STAGE((s + 1) & 1, jbase + (s + 1) * JT);
    const char* lb = lds + (s & 1) * TILEB;
    #pragma unroll
    for (int ct = 0; ct < 4; ++ct) {
      const char* lbr = lb + ct * 8192 + lrow * ROWB;
      bf16x8 bf[8];
      #pragma unroll
      for (int kk = 0; kk < 8; ++kk)
        bf[kk] = *(const bf16x8*)(lbr + koff[kk]);
      f32x4 c0 = {0.f, 0.f, 0.f, 0.f};
      f32x4 c1 = {0.f, 0.f, 0.f, 0.f};
      #pragma unroll
      for (int kk = 0; kk < 8; ++kk) {
        c0 = __builtin_amdgcn_mfma_f32_16x16x32_bf16(af[0][kk], bf[kk], c0, 0, 0, 0);
        c1 = __builtin_amdgcn_mfma_f32_16x16x32_bf16(af[1][kk], bf[kk], c1, 0, 0, 0);
      }
      #pragma unroll
      for (int r = 0; r < 4; ++r) {
        float e0 = FEXP2(fmaf(c0[r], K1F, -K1F));
        float e1 = FEXP2(fmaf(c1[r], K1F, -K1F));
        sacc[0][r] += e0;
        sacc[1][r] += e1;
        cacc[s * 4 + ct] += e0 + e1;
      }
    }
    __syncthreads();
  }
  #undef STAGE

  // ---- row-sums: reduce over the 16 col-lanes; write slot u ----
  #pragma unroll
  for (int rf = 0; rf < 2; ++rf) {
    #pragma unroll
    for (int r = 0; r < 4; ++r) {
      float v = sacc[rf][r];
      #pragma unroll
      for (int m = 1; m < 16; m <<= 1) v += __shfl_xor(v, m, 64);
      if (lrow == 0) {
        int grow = r0 + rf * 16 + kgrp * 4 + r;
        s_part[(size_t)grow * NT + u] = v;
      }
    }
  }

  // ---- col-sums: reduce over kgrp, cross-wave via LDS; write slot t ----
  #pragma unroll
  for (int idx = 0; idx < 8; ++idx) {
    float v = cacc[idx];
    v += __shfl_xor(v, 16, 64);
    v += __shfl_xor(v, 32, 64);
    if (kgrp == 0) cred[wave][idx * 16 + lrow] = v;
  }
  __syncthreads();
  if (t != u && threadIdx.x < 128) {
    int c = threadIdx.x;
    float v = cred[0][c] + cred[1][c] + cred[2][c] + cred[3][c];
    s_part[(size_t)(jbase + c) * NT + t] = v;
  }
}

// ---------------- Kernel 3: per-row term (pos dot + assemble) --------------
__global__ __launch_bounds__(256) void rowterm_kernel(
    const char* __restrict__ zb, const float* __restrict__ s_part,
    const float* __restrict__ selfdot, float* __restrict__ bpart) {
  int wave = threadIdx.x >> 6;
  int lane = threadIdx.x & 63;
  int rbase = blockIdx.x * 64 + wave * 16;
  float wacc = 0.f;
  for (int rr = 0; rr < 16; ++rr) {
    int i = rbase + rr;
    int j = i ^ BHALF;                       // (i+B) mod 2B
    int wo = (lane * 8) ^ ((i & 7) << 4);    // j&7 == i&7 (4096 % 8 == 0)
    ushort4 zi = *(const ushort4*)(zb + (size_t)i * ROWB + wo);
    ushort4 zj = *(const ushort4*)(zb + (size_t)j * ROWB + wo);
    float dot = bfu(zi.x) * bfu(zj.x) + bfu(zi.y) * bfu(zj.y) +
                bfu(zi.z) * bfu(zj.z) + bfu(zi.w) * bfu(zj.w);
    float sp = s_part[(size_t)i * NT + lane];  // 64 slots, coalesced
    #pragma unroll
    for (int m = 1; m < 64; m <<= 1) {
      dot += __shfl_xor(dot, m, 64);
      sp += __shfl_xor(sp, m, 64);
    }
    float s = sp - FEXP2(fmaf(selfdot[i], K1F, -K1F));  // remove diagonal
    wacc += 2.0f + FLOG2(s) * LN2F - 2.0f * dot;        // denom - pos
  }
  __shared__ float red[4];
  if (lane == 0) red[wave] = wacc;
  __syncthreads();
  if (threadIdx.x == 0)
    bpart[blockIdx.x] = red[0] + red[1] + red[2] + red[3];
}

// ---------------- Kernel 4: final sum --------------------------------------
__global__ __launch_bounds__(128) void final_kernel(
    const float* __restrict__ bpart, float* __restrict__ out) {
  int t = threadIdx.x;  // 128 threads = 2 waves
  float v = bpart[t];
  #pragma unroll
  for (int m = 1; m < 64; m <<= 1) v += __shfl_xor(v, m, 64);
  __shared__ float r2[2];
  if ((t & 63) == 0) r2[t >> 6] = v;
  __syncthreads();
  if (t == 0) out[0] = (r2[0] + r2[1]) / (float)NROWS;
}

// ---------------- Launcher --------------------------------------------------
extern "C" void kernel_launch(void* const* d_in, const int* in_sizes, int n_in,
                              void* d_out, int out_size, void* d_ws, size_t ws_size,
                              hipStream_t stream) {
  const float* a = (const float*)d_in[0];
  const float* b = (const float*)d_in[1];
  float* out = (float*)d_out;
  char* ws = (char*)d_ws;

  char* zb = ws;                                            // 4 MiB
  float* selfdot = (float*)(ws + (size_t)NROWS * ROWB);     // 32 KiB
  float* s_part = selfdot + NROWS;                          // 2 MiB [8192][64]
  float* bpart = s_part + (size_t)NROWS * NT;               // 512 B

  hipLaunchKernelGGL(norm_kernel, dim3(NROWS / 4), dim3(256), 0, stream,
                     a, b, zb, selfdot);
  hipLaunchKernelGGL(sim_kernel, dim3(NT * (NT + 1) / 2), dim3(256), 0,
                     stream, zb, s_part);
  hipLaunchKernelGGL(rowterm_kernel, dim3(128), dim3(256), 0, stream,
                     zb, s_part, selfdot, bpart);
  hipLaunchKernelGGL(final_kernel, dim3(1), dim3(128), 0, stream, bpart, out);
}

// Round 5
// 54.219 us; speedup vs baseline: 1.0939x; 1.0939x over previous
//
#include <hip/hip_runtime.h>
#include <hip/hip_bf16.h>
#include <math.h>

// SimCLR NT-Xent: B=4096, D=256, n=8192, T=0.5.
// z' = sqrt(K1) * rownorm(concat(a,b)) as bf16, row-swizzled:
//   stored_byte_in_row = logical_byte ^ ((row&7)<<4)
// MFMA(z', z'^T) = K1 * dot  (K1 = 2*log2 e), so exp(sim_ij) = exp2(MFMA out)
// with NO per-element fma. E is symmetric -> triangular strip tiling:
// block (t,g) computes tiles (t, u=(t+g*4+k)%64), k=0..3 (g=8: single d=32
// tile, t<32 only). Row-side sums -> slot d; col-side sums -> slot 64-d.
// Each s_part[row][slot] written exactly once.
// loss = mean( ln2 * (log2(S_i - exp2(self_i)) - posdot_scaled_i) ).

#define NROWS 8192
#define BHALF 4096
#define DDIM  256
#define ROWB  512                 // bytes per bf16 row
#define NT    64                  // number of 128-row tiles
#define TILEB 32768               // 64 cols * 512B per LDS buffer

#define SQRT_K1 1.6986436f        // sqrt(2*log2(e))
#define LN2F 0.6931471805599453f

typedef __attribute__((ext_vector_type(8))) __bf16 bf16x8;
typedef __attribute__((ext_vector_type(4))) float f32x4;

#if __has_builtin(__builtin_amdgcn_exp2f)
#define FEXP2(x) __builtin_amdgcn_exp2f(x)
#else
#define FEXP2(x) __exp2f(x)
#endif
#if __has_builtin(__builtin_amdgcn_logf)
#define FLOG2(x) __builtin_amdgcn_logf(x)
#else
#define FLOG2(x) __log2f(x)
#endif

__device__ __forceinline__ float bfu(unsigned short u) {
  union { unsigned v; float f; } x; x.v = ((unsigned)u) << 16; return x.f;
}

// ---------------- Kernel 1: normalize+scale rows -> swizzled bf16 ----------
__global__ __launch_bounds__(256) void norm_kernel(
    const float* __restrict__ a, const float* __restrict__ b,
    char* __restrict__ zb, float* __restrict__ selfdot) {
  int row = blockIdx.x * 4 + (threadIdx.x >> 6);
  int lane = threadIdx.x & 63;
  const float* src = (row < BHALF) ? (a + (size_t)row * DDIM)
                                   : (b + (size_t)(row - BHALF) * DDIM);
  float4 v = ((const float4*)src)[lane];
  float ss = v.x * v.x + v.y * v.y + v.z * v.z + v.w * v.w;
  #pragma unroll
  for (int m = 1; m < 64; m <<= 1) ss += __shfl_xor(ss, m, 64);
  float inv = rsqrtf(ss);
  inv = inv * (1.5f - 0.5f * ss * inv * inv);
  float sc = inv * SQRT_K1;   // bake sqrt(K1) into both operands

  union { __hip_bfloat16 h; unsigned short u; } c0, c1, c2, c3;
  c0.h = __float2bfloat16(v.x * sc);
  c1.h = __float2bfloat16(v.y * sc);
  c2.h = __float2bfloat16(v.z * sc);
  c3.h = __float2bfloat16(v.w * sc);
  // scaled self-dot of the bf16-rounded row (= what MFMA produces on diag)
  float q0 = bfu(c0.u), q1 = bfu(c1.u), q2 = bfu(c2.u), q3 = bfu(c3.u);
  float sq = q0 * q0 + q1 * q1 + q2 * q2 + q3 * q3;
  #pragma unroll
  for (int m = 1; m < 64; m <<= 1) sq += __shfl_xor(sq, m, 64);

  ushort4 o = make_ushort4(c0.u, c1.u, c2.u, c3.u);
  int off = row * ROWB + ((lane * 8) ^ ((row & 7) << 4));
  *(ushort4*)(zb + off) = o;
  if (lane == 0) selfdot[row] = sq;
}

// ---------------- Kernel 2: triangular strips, z z^T + exp2-sum ------------
// Grid (64, 9): t = x, g = y. g<8: 4 tiles d=g*4..g*4+3; g==8: d=32, t<32.
// 4 waves x 32 rows; 8-step double-buffered LDS pipeline across the strip.
__global__ __launch_bounds__(256, 2) void sim_kernel(
    const char* __restrict__ zb, float* __restrict__ s_part) {
  __shared__ __align__(16) char lds[2 * TILEB];  // 64 KiB
  __shared__ float cred[4][512];                 // per-wave col partials 8 KiB

  int t = blockIdx.x, g = blockIdx.y;
  if (g == 8 && t >= 32) return;
  int ntile = (g == 8) ? 1 : 4;

  int wave = threadIdx.x >> 6;
  int lane = threadIdx.x & 63;
  int lrow = lane & 15;
  int kgrp = lane >> 4;
  int sw = (lrow & 7) << 4;
  int r0 = t * 128 + wave * 32;

  int koff[8];
  #pragma unroll
  for (int kk = 0; kk < 8; ++kk) koff[kk] = (kk * 64 + kgrp * 16) ^ sw;

  // --- preload A fragments (32 rows x K=256), scaled z ---
  bf16x8 af[2][8];
  #pragma unroll
  for (int rf = 0; rf < 2; ++rf) {
    const char* rp = zb + (size_t)(r0 + rf * 16 + lrow) * ROWB;
    #pragma unroll
    for (int kk = 0; kk < 8; ++kk)
      af[rf][kk] = *(const bf16x8*)(rp + koff[kk]);
  }

  float2 sacc2[4];                 // .x = rf0, .y = rf1 row-sum acc
  #pragma unroll
  for (int r = 0; r < 4; ++r) sacc2[r] = make_float2(0.f, 0.f);
  float cacc[8] = {};              // per-tile col-group acc [s*4+ct]

  #define STAGE(buf, rowbase) do {                                            \
    const char* g_ = zb + (size_t)(rowbase) * ROWB + wave * 8192 + lane * 16; \
    char* l_ = lds + (buf) * TILEB + wave * 8192;                             \
    _Pragma("unroll")                                                         \
    for (int c8 = 0; c8 < 8; ++c8)                                            \
      __builtin_amdgcn_global_load_lds(                                       \
          (const __attribute__((address_space(1))) void*)(g_ + c8 * 1024),    \
          (__attribute__((address_space(3))) void*)(l_ + c8 * 1024),          \
          16, 0, 0);                                                          \
  } while (0)

  STAGE(0, ((t + g * 4) & 63) * 128);
  __syncthreads();

  for (int k = 0; k < ntile; ++k) {
    int d = g * 4 + k;
    int u = (t + d) & 63;
    #pragma unroll
    for (int s = 0; s < 2; ++s) {
      if (s == 0) {
        STAGE(1, u * 128 + 64);
      } else if (k + 1 < ntile) {
        STAGE(0, ((t + d + 1) & 63) * 128);
      }
      const char* lb = lds + s * TILEB;
      #pragma unroll
      for (int ct = 0; ct < 4; ++ct) {
        const char* lbr = lb + ct * 8192 + lrow * ROWB;
        bf16x8 bf[8];
        #pragma unroll
        for (int kk = 0; kk < 8; ++kk)
          bf[kk] = *(const bf16x8*)(lbr + koff[kk]);
        f32x4 c0 = {0.f, 0.f, 0.f, 0.f};
        f32x4 c1 = {0.f, 0.f, 0.f, 0.f};
        #pragma unroll
        for (int kk = 0; kk < 8; ++kk) {
          c0 = __builtin_amdgcn_mfma_f32_16x16x32_bf16(af[0][kk], bf[kk], c0, 0, 0, 0);
          c1 = __builtin_amdgcn_mfma_f32_16x16x32_bf16(af[1][kk], bf[kk], c1, 0, 0, 0);
        }
        float2 ex[4];
        #pragma unroll
        for (int r = 0; r < 4; ++r) {
          ex[r].x = FEXP2(c0[r]);          // = exp(sim), no fma needed
          ex[r].y = FEXP2(c1[r]);
          sacc2[r].x += ex[r].x;           // packed-friendly adds
          sacc2[r].y += ex[r].y;
        }
        float2 cs01 = make_float2(ex[0].x + ex[1].x, ex[0].y + ex[1].y);
        float2 cs23 = make_float2(ex[2].x + ex[3].x, ex[2].y + ex[3].y);
        cacc[s * 4 + ct] += (cs01.x + cs23.x) + (cs01.y + cs23.y);
      }
      __syncthreads();
    }
    // ---- flush tile k: row-sums (slot d) ----
    #pragma unroll
    for (int rf = 0; rf < 2; ++rf) {
      #pragma unroll
      for (int r = 0; r < 4; ++r) {
        float v = rf ? sacc2[r].y : sacc2[r].x;
        #pragma unroll
        for (int m = 1; m < 16; m <<= 1) v += __shfl_xor(v, m, 64);
        if (lrow == 0)
          s_part[(size_t)(r0 + rf * 16 + kgrp * 4 + r) * NT + d] = v;
      }
    }
    #pragma unroll
    for (int r = 0; r < 4; ++r) sacc2[r] = make_float2(0.f, 0.f);
    // ---- col partials -> wave-private cred (no barrier needed) ----
    #pragma unroll
    for (int idx = 0; idx < 8; ++idx) {
      float v = cacc[idx];
      v += __shfl_xor(v, 16, 64);
      v += __shfl_xor(v, 32, 64);
      if (kgrp == 0) cred[wave][k * 128 + idx * 16 + lrow] = v;
      cacc[idx] = 0.f;
    }
  }
  #undef STAGE

  __syncthreads();
  // ---- col-sums: cross-wave sum, write slot 64-d (skip diagonal tile) ----
  for (int cc = threadIdx.x; cc < ntile * 128; cc += 256) {
    int k = cc >> 7;
    int d = g * 4 + k;
    if (d == 0) continue;
    int u = (t + d) & 63;
    float v = cred[0][cc] + cred[1][cc] + cred[2][cc] + cred[3][cc];
    s_part[(size_t)(u * 128 + (cc & 127)) * NT + (64 - d)] = v;
  }
}

// ---------------- Kernel 3: per-row term (pos dot + assemble) --------------
__global__ __launch_bounds__(256) void rowterm_kernel(
    const char* __restrict__ zb, const float* __restrict__ s_part,
    const float* __restrict__ selfdot, float* __restrict__ bpart) {
  int wave = threadIdx.x >> 6;
  int lane = threadIdx.x & 63;
  int rbase = blockIdx.x * 64 + wave * 16;
  float wacc = 0.f;
  for (int rr = 0; rr < 16; ++rr) {
    int i = rbase + rr;
    int j = i ^ BHALF;                       // (i+B) mod 2B
    int wo = (lane * 8) ^ ((i & 7) << 4);    // j&7 == i&7 (4096 % 8 == 0)
    ushort4 zi = *(const ushort4*)(zb + (size_t)i * ROWB + wo);
    ushort4 zj = *(const ushort4*)(zb + (size_t)j * ROWB + wo);
    float dot = bfu(zi.x) * bfu(zj.x) + bfu(zi.y) * bfu(zj.y) +
                bfu(zi.z) * bfu(zj.z) + bfu(zi.w) * bfu(zj.w);
    float sp = s_part[(size_t)i * NT + lane];  // 64 slots, coalesced
    #pragma unroll
    for (int m = 1; m < 64; m <<= 1) {
      dot += __shfl_xor(dot, m, 64);
      sp += __shfl_xor(sp, m, 64);
    }
    float S = sp - FEXP2(selfdot[i]);          // remove diagonal
    wacc += LN2F * (FLOG2(S) - dot);           // denom - pos (2's cancel)
  }
  __shared__ float red[4];
  if (lane == 0) red[wave] = wacc;
  __syncthreads();
  if (threadIdx.x == 0)
    bpart[blockIdx.x] = red[0] + red[1] + red[2] + red[3];
}

// ---------------- Kernel 4: final sum --------------------------------------
__global__ __launch_bounds__(128) void final_kernel(
    const float* __restrict__ bpart, float* __restrict__ out) {
  int t = threadIdx.x;  // 128 threads = 2 waves
  float v = bpart[t];
  #pragma unroll
  for (int m = 1; m < 64; m <<= 1) v += __shfl_xor(v, m, 64);
  __shared__ float r2[2];
  if ((t & 63) == 0) r2[t >> 6] = v;
  __syncthreads();
  if (t == 0) out[0] = (r2[0] + r2[1]) / (float)NROWS;
}

// ---------------- Launcher --------------------------------------------------
extern "C" void kernel_launch(void* const* d_in, const int* in_sizes, int n_in,
                              void* d_out, int out_size, void* d_ws, size_t ws_size,
                              hipStream_t stream) {
  const float* a = (const float*)d_in[0];
  const float* b = (const float*)d_in[1];
  float* out = (float*)d_out;
  char* ws = (char*)d_ws;

  char* zb = ws;                                            // 4 MiB
  float* selfdot = (float*)(ws + (size_t)NROWS * ROWB);     // 32 KiB
  float* s_part = selfdot + NROWS;                          // 2 MiB [8192][64]
  float* bpart = s_part + (size_t)NROWS * NT;               // 512 B

  hipLaunchKernelGGL(norm_kernel, dim3(NROWS / 4), dim3(256), 0, stream,
                     a, b, zb, selfdot);
  hipLaunchKernelGGL(sim_kernel, dim3(64, 9), dim3(256), 0, stream,
                     zb, s_part);
  hipLaunchKernelGGL(rowterm_kernel, dim3(128), dim3(256), 0, stream,
                     zb, s_part, selfdot, bpart);
  hipLaunchKernelGGL(final_kernel, dim3(1), dim3(128), 0, stream, bpart, out);
}